// Round 1
// 599.913 us; speedup vs baseline: 1.1164x; 1.1164x over previous
//
#include <hip/hip_runtime.h>
#include <hip/hip_bf16.h>
#include <cstdint>

// ---------- bf16 helpers (raw ushort representation) ----------
__device__ __forceinline__ unsigned short f2b(float f) {
    union { float f; unsigned int i; } v; v.f = f;
    unsigned int i = v.i;
    unsigned int r = (i + 0x7FFFu + ((i >> 16) & 1u)) >> 16;   // RNE, finite inputs
    return (unsigned short)r;
}
__device__ __forceinline__ float b2f_lo(unsigned int p) {
    union { unsigned int i; float f; } v; v.i = p << 16; return v.f;
}
__device__ __forceinline__ float b2f_hi(unsigned int p) {
    union { unsigned int i; float f; } v; v.i = p & 0xFFFF0000u; return v.f;
}
__device__ __forceinline__ unsigned int pack2(float a, float b) {
    return (unsigned int)f2b(a) | ((unsigned int)f2b(b) << 16);
}

typedef __attribute__((__ext_vector_type__(8))) __bf16 bf16x8;
typedef __attribute__((__ext_vector_type__(4))) float  f32x4;

#define N_NODES 100000
#define N_EDGES 3200000
#define NBUCK   200        // coarse buckets
#define BSZ     500        // nodes per bucket (200*500 = 100000)

// ---------- 1. coarse histograms (dst and src) — LDS-privatized ----------
__global__ void k_hist2(const int* __restrict__ src, const int* __restrict__ dst,
                        int* __restrict__ gcntA, int* __restrict__ gcntB, int E) {
    __shared__ int hA[NBUCK], hB[NBUCK];
    int t = threadIdx.x;
    if (t < NBUCK) { hA[t] = 0; hB[t] = 0; }
    __syncthreads();
    for (int i = blockIdx.x * blockDim.x + t; i < E; i += gridDim.x * blockDim.x) {
        atomicAdd(&hA[dst[i] / BSZ], 1);
        atomicAdd(&hB[src[i] / BSZ], 1);
    }
    __syncthreads();
    if (t < NBUCK) {
        if (hA[t]) atomicAdd(&gcntA[t], hA[t]);
        if (hB[t]) atomicAdd(&gcntB[t], hB[t]);
    }
}

// ---------- 2. scan coarse counts -> bucket bases + cursors ----------
__global__ void k_scan_coarse(const int* __restrict__ gcntA, const int* __restrict__ gcntB,
                              int* __restrict__ gbaseA, int* __restrict__ gbaseB,
                              int* __restrict__ gcurA, int* __restrict__ gcurB,
                              int* __restrict__ offsets) {
    __shared__ int pA[256], pB[256];
    int t = threadIdx.x;
    int vA = (t < NBUCK) ? gcntA[t] : 0;
    int vB = (t < NBUCK) ? gcntB[t] : 0;
    pA[t] = vA; pB[t] = vB;
    __syncthreads();
    for (int d = 1; d < 256; d <<= 1) {
        int a = (t >= d) ? pA[t - d] : 0;
        int b = (t >= d) ? pB[t - d] : 0;
        __syncthreads();
        pA[t] += a; pB[t] += b;
        __syncthreads();
    }
    if (t < NBUCK) {
        gbaseA[t] = pA[t] - vA; gcurA[t] = pA[t] - vA;
        gbaseB[t] = pB[t] - vB; gcurB[t] = pB[t] - vB;
    }
    if (t == 255) {
        gbaseA[NBUCK] = pA[255];
        gbaseB[NBUCK] = pB[255];
        offsets[N_NODES] = pA[255];   // == E
    }
}

// ---------- 3. scatter edges to coarse buckets (pairs by dst, keys by src) ----------
__global__ void k_scatter(const int* __restrict__ src, const int* __restrict__ dst,
                          int* __restrict__ gcurA, int* __restrict__ gcurB,
                          uint2* __restrict__ pairs, int* __restrict__ keysB, int E) {
    __shared__ int hA[NBUCK], hB[NBUCK], baA[NBUCK], baB[NBUCK], lcA[NBUCK], lcB[NBUCK];
    int t = threadIdx.x;
    const int CHUNK = 12500;                       // E / 256 blocks
    int lo = blockIdx.x * CHUNK, hi = min(lo + CHUNK, E);
    if (t < NBUCK) { hA[t] = 0; hB[t] = 0; }
    __syncthreads();
    for (int i = lo + t; i < hi; i += 256) {
        atomicAdd(&hA[dst[i] / BSZ], 1);
        atomicAdd(&hB[src[i] / BSZ], 1);
    }
    __syncthreads();
    if (t < NBUCK) {
        baA[t] = hA[t] ? atomicAdd(&gcurA[t], hA[t]) : 0;
        lcA[t] = 0;
        baB[t] = hB[t] ? atomicAdd(&gcurB[t], hB[t]) : 0;
        lcB[t] = 0;
    }
    __syncthreads();
    for (int i = lo + t; i < hi; i += 256) {
        int s = src[i], d = dst[i];
        int bA = d / BSZ;
        int l  = atomicAdd(&lcA[bA], 1);
        pairs[baA[bA] + l] = make_uint2((unsigned)s, (unsigned)d);
        int bB = s / BSZ;
        int l2 = atomicAdd(&lcB[bB], 1);
        keysB[baB[bB] + l2] = s;
    }
}

// ---------- 4. per-bucket CSR finalize: offsets, in_norm, esrc ----------
__global__ void k_csr_bucket(const uint2* __restrict__ pairs, const int* __restrict__ gbaseA,
                             int* __restrict__ offsets, float* __restrict__ in_norm,
                             int* __restrict__ esrc) {
    __shared__ int hist[512], scan[512], curs[512];
    int b = blockIdx.x, t = threadIdx.x;
    int node0 = b * BSZ;
    int bstart = gbaseA[b], bend = gbaseA[b + 1];
    if (t < 512) hist[t] = 0;
    __syncthreads();
    for (int i = bstart + t; i < bend; i += 1024)
        atomicAdd(&hist[(int)pairs[i].y - node0], 1);
    __syncthreads();
    if (t < 512) scan[t] = hist[t];
    __syncthreads();
    for (int d = 1; d < 512; d <<= 1) {
        int v = (t < 512 && t >= d) ? scan[t - d] : 0;
        __syncthreads();
        if (t < 512) scan[t] += v;
        __syncthreads();
    }
    if (t < BSZ) {
        int excl = scan[t] - hist[t];
        offsets[node0 + t] = bstart + excl;
        in_norm[node0 + t] = rsqrtf((float)max(hist[t], 1));
        curs[t] = excl;
    }
    __syncthreads();
    for (int i = bstart + t; i < bend; i += 1024) {
        uint2 p = pairs[i];
        int d = (int)p.y - node0;
        int l = atomicAdd(&curs[d], 1);
        esrc[bstart + l] = (int)p.x;
    }
}

// ---------- 4b. canonicalize: wave-parallel bitonic sort of each segment ----------
__global__ void k_sortwave(const int* __restrict__ offsets, int* __restrict__ esrc, int N) {
    int node = blockIdx.x * 4 + (threadIdx.x >> 6);
    if (node >= N) return;
    int lane = threadIdx.x & 63;
    int lo = offsets[node], hi = offsets[node + 1];
    int len = hi - lo;
    if (len <= 1) return;
    const int INF = 0x7FFFFFFF;
    int v0 = (lane < len) ? esrc[lo + lane] : INF;
    int v1 = (64 + lane < len) ? esrc[lo + 64 + lane] : INF;
#pragma unroll
    for (int k = 2; k <= 128; k <<= 1) {
#pragma unroll
        for (int d = 64; d > 0; d >>= 1) {
            if (d >= k) continue;
            if (d == 64) {
                int a = min(v0, v1), b = max(v0, v1);
                v0 = a; v1 = b;
            } else {
                int w0 = __shfl_xor(v0, d, 64);
                int w1 = __shfl_xor(v1, d, 64);
                bool up0 = ((lane & k) == 0);
                bool up1 = (((64 + lane) & k) == 0);
                bool lower = ((lane & d) == 0);
                v0 = (lower == up0) ? min(v0, w0) : max(v0, w0);
                v1 = (lower == up1) ? min(v1, w1) : max(v1, w1);
            }
        }
    }
    if (lane < len) esrc[lo + lane] = v0;
    if (64 + lane < len) esrc[lo + 64 + lane] = v1;
}

// ---------- 5. per-bucket src count -> out_norm ----------
__global__ void k_count_bucket(const int* __restrict__ keys, const int* __restrict__ gbaseB,
                               float* __restrict__ out_norm) {
    __shared__ int hist[512];
    int b = blockIdx.x, t = threadIdx.x;
    int node0 = b * BSZ;
    int bstart = gbaseB[b], bend = gbaseB[b + 1];
    if (t < 512) hist[t] = 0;
    __syncthreads();
    for (int i = bstart + t; i < bend; i += 1024)
        atomicAdd(&hist[keys[i] - node0], 1);
    __syncthreads();
    if (t < BSZ) out_norm[node0 + t] = rsqrtf((float)max(hist[t], 1));
}

// ---------- 6. xs = bf16(x * out_norm), fp32 -> bf16 ----------
__global__ void k_scale(const float4* __restrict__ x4, const float* __restrict__ out_norm,
                        uint2* __restrict__ xs, int total4) {
    int i = blockIdx.x * blockDim.x + threadIdx.x;
    if (i < total4) {
        int node = i >> 5;                 // 32 float4 per node
        float on = out_norm[node];
        float4 v = x4[i];
        uint2 o;
        o.x = pack2(v.x * on, v.y * on);
        o.y = pack2(v.z * on, v.w * on);
        xs[i] = o;
    }
}

// ---------- 7. merged weight transpose + bf16 cast (all four weights) ----------
__global__ void k_transpose4(const float* __restrict__ w1, const float* __restrict__ w2,
                             const float* __restrict__ wm1, const float* __restrict__ wm2,
                             unsigned short* __restrict__ t1, unsigned short* __restrict__ t2,
                             unsigned short* __restrict__ tm1, unsigned short* __restrict__ tm2) {
    int i = blockIdx.x * blockDim.x + threadIdx.x;
    const float* w; unsigned short* t; int N, idx;
    if (i < 16384)       { w = w1;  t = t1;  N = 128; idx = i; }
    else if (i < 32768)  { w = w2;  t = t2;  N = 128; idx = i - 16384; }
    else if (i < 65536)  { w = wm1; t = tm1; N = 256; idx = i - 32768; }
    else if (i < 81920)  { w = wm2; t = tm2; N = 64;  idx = i - 65536; }
    else return;
    int K = (i < 65536) ? 128 : 256;
    int k = idx / N, n = idx - k * N;
    t[(size_t)n * K + k] = f2b(w[idx]);
}

// ---------- aggregate inner body (identical edge/sum order to the verified R6 kernel) ----------
// wave aggregates one node; lane = g*16 + c. Returns 8 per-lane partial sums reduced
// across the 4 edge-subgroups; g==0 lanes hold the final row chunk c.
#define AGG_NODE_BODY(node)                                                     \
    int lo = offsets[node], hi = offsets[node + 1];                             \
    float a0 = 0.f, a1 = 0.f, a2 = 0.f, a3 = 0.f,                               \
          a4 = 0.f, a5 = 0.f, a6 = 0.f, a7 = 0.f;                               \
    int k = lo + g;                                                             \
    for (; k + 12 < hi; k += 16) {                                              \
        int s0 = esrc[k];                                                       \
        int s1 = esrc[k + 4];                                                   \
        int s2 = esrc[k + 8];                                                   \
        int s3 = esrc[k + 12];                                                  \
        uint4 p0 = feat[(size_t)s0 * 16 + c];                                   \
        uint4 p1 = feat[(size_t)s1 * 16 + c];                                   \
        uint4 p2 = feat[(size_t)s2 * 16 + c];                                   \
        uint4 p3 = feat[(size_t)s3 * 16 + c];                                   \
        a0 += b2f_lo(p0.x); a1 += b2f_hi(p0.x);                                 \
        a2 += b2f_lo(p0.y); a3 += b2f_hi(p0.y);                                 \
        a4 += b2f_lo(p0.z); a5 += b2f_hi(p0.z);                                 \
        a6 += b2f_lo(p0.w); a7 += b2f_hi(p0.w);                                 \
        a0 += b2f_lo(p1.x); a1 += b2f_hi(p1.x);                                 \
        a2 += b2f_lo(p1.y); a3 += b2f_hi(p1.y);                                 \
        a4 += b2f_lo(p1.z); a5 += b2f_hi(p1.z);                                 \
        a6 += b2f_lo(p1.w); a7 += b2f_hi(p1.w);                                 \
        a0 += b2f_lo(p2.x); a1 += b2f_hi(p2.x);                                 \
        a2 += b2f_lo(p2.y); a3 += b2f_hi(p2.y);                                 \
        a4 += b2f_lo(p2.z); a5 += b2f_hi(p2.z);                                 \
        a6 += b2f_lo(p2.w); a7 += b2f_hi(p2.w);                                 \
        a0 += b2f_lo(p3.x); a1 += b2f_hi(p3.x);                                 \
        a2 += b2f_lo(p3.y); a3 += b2f_hi(p3.y);                                 \
        a4 += b2f_lo(p3.z); a5 += b2f_hi(p3.z);                                 \
        a6 += b2f_lo(p3.w); a7 += b2f_hi(p3.w);                                 \
    }                                                                           \
    for (; k < hi; k += 4) {                                                    \
        int s = esrc[k];                                                        \
        uint4 p = feat[(size_t)s * 16 + c];                                     \
        a0 += b2f_lo(p.x); a1 += b2f_hi(p.x);                                   \
        a2 += b2f_lo(p.y); a3 += b2f_hi(p.y);                                   \
        a4 += b2f_lo(p.z); a5 += b2f_hi(p.z);                                   \
        a6 += b2f_lo(p.w); a7 += b2f_hi(p.w);                                   \
    }                                                                           \
    a0 += __shfl_xor(a0, 16, 64); a0 += __shfl_xor(a0, 32, 64);                 \
    a1 += __shfl_xor(a1, 16, 64); a1 += __shfl_xor(a1, 32, 64);                 \
    a2 += __shfl_xor(a2, 16, 64); a2 += __shfl_xor(a2, 32, 64);                 \
    a3 += __shfl_xor(a3, 16, 64); a3 += __shfl_xor(a3, 32, 64);                 \
    a4 += __shfl_xor(a4, 16, 64); a4 += __shfl_xor(a4, 32, 64);                 \
    a5 += __shfl_xor(a5, 16, 64); a5 += __shfl_xor(a5, 32, 64);                 \
    a6 += __shfl_xor(a6, 16, 64); a6 += __shfl_xor(a6, 32, 64);                 \
    a7 += __shfl_xor(a7, 16, 64); a7 += __shfl_xor(a7, 32, 64);

// ---------- 8. fused conv: aggregate(32 nodes) -> LDS -> MFMA GEMM -> relu(/scale) ----------
// Block: 256 threads = 4 waves, 32 nodes (one GEMM M-tile). Each wave aggregates 8
// nodes sequentially (same per-node edge order as before -> bit-identical sums), then
// the block GEMMs the 32x128 LDS tile against WT (each wave: 32 cols).
__global__ void k_conv(const int* __restrict__ offsets, const int* __restrict__ esrc,
                       const uint4* __restrict__ feat, const float* __restrict__ in_norm,
                       const unsigned short* __restrict__ WT, const float* __restrict__ bias,
                       const float* __restrict__ row_scale, unsigned short* __restrict__ C,
                       int N) {
    __shared__ unsigned short A[32][136];       // 272B row stride, 16B-aligned rows
    int wv = threadIdx.x >> 6, lane = threadIdx.x & 63;
    int row0 = blockIdx.x * 32;
    int g = lane >> 4, c = lane & 15;

    // phase A: aggregate
    for (int i = 0; i < 8; ++i) {
        int nl = wv * 8 + i;
        int node = row0 + nl;
        AGG_NODE_BODY(node)
        if (g == 0) {
            float inn = in_norm[node];
            uint4 o;
            o.x = pack2(a0 * inn, a1 * inn);
            o.y = pack2(a2 * inn, a3 * inn);
            o.z = pack2(a4 * inn, a5 * inn);
            o.w = pack2(a6 * inn, a7 * inn);
            *(uint4*)&A[nl][c * 8] = o;
        }
    }
    __syncthreads();

    // phase B: GEMM 32x128 tile, wave covers cols wv*32 .. wv*32+31
    int m = lane & 15, q = lane >> 4;
    const unsigned short* b0 = WT + (size_t)(wv * 32 + m) * 128 + q * 8;
    const unsigned short* b1 = b0 + (size_t)16 * 128;
    f32x4 acc00 = {0.f, 0.f, 0.f, 0.f}, acc10 = {0.f, 0.f, 0.f, 0.f};
    f32x4 acc01 = {0.f, 0.f, 0.f, 0.f}, acc11 = {0.f, 0.f, 0.f, 0.f};
#pragma unroll
    for (int k = 0; k < 128; k += 32) {
        bf16x8 bf0 = *(const bf16x8*)(b0 + k);
        bf16x8 bf1 = *(const bf16x8*)(b1 + k);
        bf16x8 af0 = *(const bf16x8*)&A[m][q * 8 + k];
        bf16x8 af1 = *(const bf16x8*)&A[16 + m][q * 8 + k];
        acc00 = __builtin_amdgcn_mfma_f32_16x16x32_bf16(af0, bf0, acc00, 0, 0, 0);
        acc10 = __builtin_amdgcn_mfma_f32_16x16x32_bf16(af1, bf0, acc10, 0, 0, 0);
        acc01 = __builtin_amdgcn_mfma_f32_16x16x32_bf16(af0, bf1, acc01, 0, 0, 0);
        acc11 = __builtin_amdgcn_mfma_f32_16x16x32_bf16(af1, bf1, acc11, 0, 0, 0);
    }
    int col0 = wv * 32 + m;
    int col1 = col0 + 16;
    float bc0 = bias[col0], bc1 = bias[col1];
#pragma unroll
    for (int r = 0; r < 4; r++) {
        int rr = row0 + q * 4 + r;
        int rr1 = rr + 16;
        float v00 = fmaxf(acc00[r] + bc0, 0.f);
        float v10 = fmaxf(acc10[r] + bc0, 0.f);
        float v01 = fmaxf(acc01[r] + bc1, 0.f);
        float v11 = fmaxf(acc11[r] + bc1, 0.f);
        if (row_scale) {
            float s0 = row_scale[rr], s1 = row_scale[rr1];
            v00 *= s0; v01 *= s0; v10 *= s1; v11 *= s1;
        }
        C[(size_t)rr * 128 + col0]  = f2b(v00);
        C[(size_t)rr * 128 + col1]  = f2b(v01);
        C[(size_t)rr1 * 128 + col0] = f2b(v10);
        C[(size_t)rr1 * 128 + col1] = f2b(v11);
    }
}

// ---------- 9. fused conv2 + MLP: aggregate -> gemm(w2)+relu -> mlp1+relu -> mlp2 ----------
// LDS: H1[32][136] at 0; A[32][136] at 8704; H2[32][264] aliased over A (A dead
// after the w2 GEMM). Total 25600 B -> 6 blocks/CU (24 waves) as before.
__global__ void k_conv2_mlp(const int* __restrict__ offsets, const int* __restrict__ esrc,
                            const uint4* __restrict__ feat, const float* __restrict__ in_norm,
                            const unsigned short* __restrict__ WT2, const float* __restrict__ b2,
                            const unsigned short* __restrict__ WTM1, const float* __restrict__ bm1,
                            const unsigned short* __restrict__ WTM2, const float* __restrict__ bm2,
                            float* __restrict__ out, int N) {
    __shared__ unsigned short smem[12800];                    // 25600 B
    unsigned short (*H1)[136] = (unsigned short(*)[136])(smem);
    unsigned short (*A)[136]  = (unsigned short(*)[136])(smem + 4352);
    unsigned short (*H2)[264] = (unsigned short(*)[264])(smem + 4352);

    int wv = threadIdx.x >> 6, lane = threadIdx.x & 63;
    int row0 = blockIdx.x * 32;
    int g = lane >> 4, c = lane & 15;

    // phase A: aggregate 32 nodes -> A
    for (int i = 0; i < 8; ++i) {
        int nl = wv * 8 + i;
        int node = row0 + nl;
        AGG_NODE_BODY(node)
        if (g == 0) {
            float inn = in_norm[node];
            uint4 o;
            o.x = pack2(a0 * inn, a1 * inn);
            o.y = pack2(a2 * inn, a3 * inn);
            o.z = pack2(a4 * inn, a5 * inn);
            o.w = pack2(a6 * inn, a7 * inn);
            *(uint4*)&A[nl][c * 8] = o;
        }
    }
    __syncthreads();

    int m = lane & 15, q = lane >> 4;

    // phase B: gemm w2 (32x128 @ 128x128) + relu -> H1 (bf16)
    {
        const unsigned short* b0 = WT2 + (size_t)(wv * 32 + m) * 128 + q * 8;
        const unsigned short* b1 = b0 + (size_t)16 * 128;
        f32x4 acc00 = {0.f, 0.f, 0.f, 0.f}, acc10 = {0.f, 0.f, 0.f, 0.f};
        f32x4 acc01 = {0.f, 0.f, 0.f, 0.f}, acc11 = {0.f, 0.f, 0.f, 0.f};
#pragma unroll
        for (int k = 0; k < 128; k += 32) {
            bf16x8 bf0 = *(const bf16x8*)(b0 + k);
            bf16x8 bf1 = *(const bf16x8*)(b1 + k);
            bf16x8 af0 = *(const bf16x8*)&A[m][q * 8 + k];
            bf16x8 af1 = *(const bf16x8*)&A[16 + m][q * 8 + k];
            acc00 = __builtin_amdgcn_mfma_f32_16x16x32_bf16(af0, bf0, acc00, 0, 0, 0);
            acc10 = __builtin_amdgcn_mfma_f32_16x16x32_bf16(af1, bf0, acc10, 0, 0, 0);
            acc01 = __builtin_amdgcn_mfma_f32_16x16x32_bf16(af0, bf1, acc01, 0, 0, 0);
            acc11 = __builtin_amdgcn_mfma_f32_16x16x32_bf16(af1, bf1, acc11, 0, 0, 0);
        }
        __syncthreads();   // all waves done reading A before H1 writes overlap? (H1 separate; this also fences A for H2 later)
        int col0 = wv * 32 + m;
        int col1 = col0 + 16;
        float bc0 = b2[col0], bc1 = b2[col1];
#pragma unroll
        for (int r = 0; r < 4; r++) {
            int rl = q * 4 + r;
            H1[rl][col0]      = f2b(fmaxf(acc00[r] + bc0, 0.f));
            H1[rl][col1]      = f2b(fmaxf(acc01[r] + bc1, 0.f));
            H1[rl + 16][col0] = f2b(fmaxf(acc10[r] + bc0, 0.f));
            H1[rl + 16][col1] = f2b(fmaxf(acc11[r] + bc1, 0.f));
        }
    }
    __syncthreads();

    // phase C: mlp1 (32x128 @ 128x256) + relu -> H2 (bf16). Wave covers 64 cols.
#pragma unroll
    for (int cb = 0; cb < 4; cb++) {
        int colh = wv * 64 + cb * 16 + m;
        const unsigned short* bp = WTM1 + (size_t)colh * 128 + q * 8;
        f32x4 acc0 = {0.f, 0.f, 0.f, 0.f};
        f32x4 acc1 = {0.f, 0.f, 0.f, 0.f};
#pragma unroll
        for (int s = 0; s < 4; s++) {
            bf16x8 bfr = *(const bf16x8*)(bp + s * 32);
            bf16x8 ha0 = *(const bf16x8*)&H1[m][s * 32 + q * 8];
            bf16x8 ha1 = *(const bf16x8*)&H1[m + 16][s * 32 + q * 8];
            acc0 = __builtin_amdgcn_mfma_f32_16x16x32_bf16(ha0, bfr, acc0, 0, 0, 0);
            acc1 = __builtin_amdgcn_mfma_f32_16x16x32_bf16(ha1, bfr, acc1, 0, 0, 0);
        }
        float bc = bm1[colh];
#pragma unroll
        for (int r = 0; r < 4; r++) {
            H2[q * 4 + r][colh]      = f2b(fmaxf(acc0[r] + bc, 0.f));
            H2[q * 4 + r + 16][colh] = f2b(fmaxf(acc1[r] + bc, 0.f));
        }
    }
    __syncthreads();

    // phase D: mlp2 (32x256 @ 256x64) -> out (fp32)
    {
        int colo = wv * 16 + m;
        const unsigned short* bp2 = WTM2 + (size_t)colo * 256 + q * 8;
        f32x4 acc0 = {0.f, 0.f, 0.f, 0.f};
        f32x4 acc1 = {0.f, 0.f, 0.f, 0.f};
#pragma unroll
        for (int s = 0; s < 8; s++) {
            bf16x8 bfr = *(const bf16x8*)(bp2 + s * 32);
            bf16x8 ha0 = *(const bf16x8*)&H2[m][s * 32 + q * 8];
            bf16x8 ha1 = *(const bf16x8*)&H2[m + 16][s * 32 + q * 8];
            acc0 = __builtin_amdgcn_mfma_f32_16x16x32_bf16(ha0, bfr, acc0, 0, 0, 0);
            acc1 = __builtin_amdgcn_mfma_f32_16x16x32_bf16(ha1, bfr, acc1, 0, 0, 0);
        }
        float bc = bm2[colo];
#pragma unroll
        for (int r = 0; r < 4; r++) {
            out[(size_t)(row0 + q * 4 + r) * 64 + colo]      = acc0[r] + bc;
            out[(size_t)(row0 + q * 4 + r + 16) * 64 + colo] = acc1[r] + bc;
        }
    }
}

extern "C" void kernel_launch(void* const* d_in, const int* in_sizes, int n_in,
                              void* d_out, int out_size, void* d_ws, size_t ws_size,
                              hipStream_t stream) {
    const float* x    = (const float*)d_in[0];
    const int*   src  = (const int*)d_in[1];
    const int*   dst  = (const int*)d_in[2];
    const float* w1   = (const float*)d_in[3];
    const float* b1   = (const float*)d_in[4];
    const float* w2   = (const float*)d_in[5];
    const float* b2   = (const float*)d_in[6];
    const float* wm1  = (const float*)d_in[7];
    const float* bm1  = (const float*)d_in[8];
    const float* wm2  = (const float*)d_in[9];
    const float* bm2  = (const float*)d_in[10];

    const int N = N_NODES;
    const int E = N_EDGES;

    char* p = (char*)d_ws;
    auto alloc = [&](size_t bytes) -> void* {
        void* r = (void*)p;
        p += (bytes + 255) & ~(size_t)255;
        return r;
    };
    int*   gcntA   = (int*)alloc(256 * 4);
    int*   gcntB   = (int*)alloc(256 * 4);
    int*   gbaseA  = (int*)alloc(256 * 4);
    int*   gbaseB  = (int*)alloc(256 * 4);
    int*   gcurA   = (int*)alloc(256 * 4);
    int*   gcurB   = (int*)alloc(256 * 4);
    int*   offsets = (int*)alloc((size_t)(N + 1) * 4);
    float* out_norm = (float*)alloc((size_t)N * 4);
    float* in_norm  = (float*)alloc((size_t)N * 4);
    int*   esrc     = (int*)alloc((size_t)E * 4);
    unsigned int* bufA = (unsigned int*)alloc((size_t)N * 128 * 2);  // xs
    unsigned int* bufB = (unsigned int*)alloc((size_t)N * 128 * 2);  // pairs (build only)
    unsigned int* bufC = (unsigned int*)alloc((size_t)N * 128 * 2);  // keysB, then h1
    unsigned short* wt1  = (unsigned short*)alloc(128 * 128 * 2);
    unsigned short* wt2  = (unsigned short*)alloc(128 * 128 * 2);
    unsigned short* wtm1 = (unsigned short*)alloc(256 * 128 * 2);
    unsigned short* wtm2 = (unsigned short*)alloc(64 * 256 * 2);
    (void)ws_size; (void)n_in; (void)in_sizes; (void)out_size;

    uint2* pairs = (uint2*)bufB;   // dead after k_csr_bucket
    int*   keysB = (int*)bufC;     // dead after k_count_bucket

    hipMemsetAsync(gcntA, 0, 256 * 4, stream);
    hipMemsetAsync(gcntB, 0, 256 * 4, stream);

    const int TB = 256;
    // CSR build via two-level LDS counting sort (no per-edge global atomics)
    k_hist2<<<dim3(256), dim3(TB), 0, stream>>>(src, dst, gcntA, gcntB, E);
    k_scan_coarse<<<dim3(1), dim3(TB), 0, stream>>>(gcntA, gcntB, gbaseA, gbaseB,
                                                    gcurA, gcurB, offsets);
    k_scatter<<<dim3(256), dim3(TB), 0, stream>>>(src, dst, gcurA, gcurB, pairs, keysB, E);
    k_csr_bucket<<<dim3(NBUCK), dim3(1024), 0, stream>>>(pairs, gbaseA, offsets, in_norm, esrc);
    // canonicalize segment order (wave bitonic) -> bit-deterministic sums
    k_sortwave<<<dim3(N / 4), dim3(TB), 0, stream>>>(offsets, esrc, N);
    k_count_bucket<<<dim3(NBUCK), dim3(1024), 0, stream>>>(keysB, gbaseB, out_norm);

    // xs = bf16(x * out_norm)
    k_scale<<<dim3((N * 32 + TB - 1) / TB), dim3(TB), 0, stream>>>(
        (const float4*)x, out_norm, (uint2*)bufA, N * 32);
    // all weight transposes (fp32 -> bf16) in one launch
    k_transpose4<<<dim3(320), dim3(TB), 0, stream>>>(w1, w2, wm1, wm2, wt1, wt2, wtm1, wtm2);

    // conv1: fused aggregate + gemm(w1) + relu + fold out_norm (bufA -> bufC)
    k_conv<<<dim3(N / 32), dim3(TB), 0, stream>>>(
        offsets, esrc, (const uint4*)bufA, in_norm, wt1, b1, out_norm,
        (unsigned short*)bufC, N);

    // conv2 + MLP: fused aggregate + gemm(w2) + mlp1 + mlp2 (bufC -> d_out)
    k_conv2_mlp<<<dim3(N / 32), dim3(TB), 0, stream>>>(
        offsets, esrc, (const uint4*)bufC, in_norm, wt2, b2, wtm1, bm1, wtm2, bm2,
        (float*)d_out, N);
}